// Round 3
// baseline (456.420 us; speedup 1.0000x reference)
//
#include <hip/hip_runtime.h>
#include <hip/hip_bf16.h>

// SimpleAugmentedCNN forward, B=16, H=W=32, NH=4, DKH=DVH=10.
// 6 dispatches: memset(acc) -> conv1(+BN-stat atomics) ->
// qkv_fused(BN-apply+relu+sstat-partials+qkv 1x1) ->
// attn_split (split-K flash, scalar K/V loads, exp2 domain) ->
// attn_combine(+fused avg-pool atomics) -> final (conv-pool matvec+attno+fc).
// conv_out never materialized (mean-pool commutes with conv taps);
// attn map never materialized (flash); attn_pre never materialized (pool fused).

#define NSPLIT 4

// ws layout (floats)
#define WS_H     0                      // 16*64*1024   = 1048576
#define WS_QKV   1048576                // 16*120*1024  = 1966080
#define WS_PART  3014656                // 65536*48     = 3145728
#define WS_ACC   6160384                // chanS 64 | chanS2 64 | sstatP 5120 | pooledA 640
#define ACC_BYTES ((64 + 64 + 5120 + 640) * 4)

__device__ __forceinline__ float fast_exp2(float x) {
#if __has_builtin(__builtin_amdgcn_exp2f)
  return __builtin_amdgcn_exp2f(x);
#else
  return exp2f(x);
#endif
}

// ---------------- conv1: 3->64, 3x3 SAME, + per-channel sum/sum2 atomics ----
__global__ __launch_bounds__(256) void conv1_kernel(
    const float* __restrict__ x, const float* __restrict__ w,
    const float* __restrict__ bias, float* __restrict__ h,
    float* __restrict__ chanS, float* __restrict__ chanS2) {
  int b = blockIdx.x >> 6, co = blockIdx.x & 63;
  int t = threadIdx.x;
  float wreg[27];
#pragma unroll
  for (int i = 0; i < 27; ++i) wreg[i] = w[co * 27 + i];
  float bv = bias[co];
  float s1 = 0.f, s2 = 0.f;
  for (int j = 0; j < 4; ++j) {
    int s = j * 256 + t;
    int yy = s >> 5, xx = s & 31;
    float acc = bv;
#pragma unroll
    for (int ci = 0; ci < 3; ++ci) {
#pragma unroll
      for (int dy = 0; dy < 3; ++dy) {
        int sy = yy + dy - 1;
        if (sy < 0 || sy > 31) continue;
#pragma unroll
        for (int dx = 0; dx < 3; ++dx) {
          int sx = xx + dx - 1;
          if (sx < 0 || sx > 31) continue;
          acc += wreg[ci * 9 + dy * 3 + dx] * x[((b * 3 + ci) * 32 + sy) * 32 + sx];
        }
      }
    }
    h[((b * 64 + co) * 32 + yy) * 32 + xx] = acc;
    s1 += acc;
    s2 += acc * acc;
  }
  __shared__ float r1[256], r2[256];
  r1[t] = s1; r2[t] = s2;
  __syncthreads();
  for (int off = 128; off > 0; off >>= 1) {
    if (t < off) { r1[t] += r1[t + off]; r2[t] += r2[t + off]; }
    __syncthreads();
  }
  if (t == 0) {
    atomicAdd(&chanS[co], r1[0]);
    atomicAdd(&chanS2[co], r2[0]);
  }
}

// ---------------- fused: BN-apply + relu + sstat partials + qkv 1x1 ----------
// grid 64 = (b, s-chunk of 256). Wave w computes 30 output channels.
__global__ __launch_bounds__(256) void qkv_fused_kernel(
    const float* __restrict__ h, const float* __restrict__ chanS,
    const float* __restrict__ chanS2, const float* __restrict__ bn_g,
    const float* __restrict__ bn_b, const float* __restrict__ qw,
    const float* __restrict__ qb, float* __restrict__ qkv,
    float* __restrict__ sstatP) {
  int b = blockIdx.x >> 2, chunk = blockIdx.x & 3;
  int t = threadIdx.x;
  __shared__ float ssc[64], ssh[64];
  __shared__ float hsL[32 * 258];   // padded stride 258 -> 2-way max on strided pass
  if (t < 64) {
    float mu = chanS[t] * (1.f / 16384.f);
    float var = chanS2[t] * (1.f / 16384.f) - mu * mu;
    float sc = bn_g[t] * rsqrtf(var + 1e-5f);
    ssc[t] = sc;
    ssh[t] = bn_b[t] - mu * sc;
  }
  int s = chunk * 256 + t;
  int wv = t >> 6;
  int co0 = wv * 30;
  float acc[30];
#pragma unroll
  for (int j = 0; j < 30; ++j) acc[j] = 0.f;

  for (int half = 0; half < 2; ++half) {
    __syncthreads();   // ssc ready (half 0) / previous half's reads done
    for (int cil = 0; cil < 32; ++cil) {
      int ci = half * 32 + cil;
      float v = h[((size_t)(b * 64 + ci) * 1024) + s];
      hsL[cil * 258 + t] = fmaxf(0.f, v * ssc[ci] + ssh[ci]);
    }
    __syncthreads();
    // sstat partials: thread (ci_loc, grp) reduces 32 contiguous cols of one row
    {
      int ci_loc = t & 31, grp = t >> 5;
      int ci = half * 32 + ci_loc;
      int row = chunk * 8 + grp;
      const float* hp = &hsL[ci_loc * 258 + grp * 32];
      float T = 0.f;
#pragma unroll
      for (int k = 0; k < 32; ++k) T += hp[k];
      float c0v = hp[0], c31v = hp[31];
      float* sp = sstatP + (size_t)(b * 64 + ci) * 5;
      atomicAdd(sp + 0, T);
      if (row == 0) atomicAdd(sp + 1, T);
      if (row == 31) atomicAdd(sp + 2, T);
      atomicAdd(sp + 3, c0v);
      atomicAdd(sp + 4, c31v);
    }
    // qkv accumulate (weights wave-uniform -> s_load)
    for (int cil = 0; cil < 32; ++cil) {
      int ci = half * 32 + cil;
      float hv = hsL[cil * 258 + t];
#pragma unroll
      for (int j = 0; j < 30; ++j) acc[j] += qw[(co0 + j) * 64 + ci] * hv;
    }
  }
#pragma unroll
  for (int j = 0; j < 30; ++j)
    qkv[((size_t)b * 120 + co0 + j) * 1024 + s] = acc[j] + qb[co0 + j];
}

// ---------------- split-K flash attention, scalar K/V, exp2 domain ----------
// grid 1024 = (bh*4+qt)*NSPLIT+ks. 256 threads = 256 queries.
// K/V addresses are wave-uniform -> SMEM (s_load); no LDS in the hot loop.
__global__ __launch_bounds__(256) void attn_split_kernel(
    const float* __restrict__ qkv, const float* __restrict__ relw,
    const float* __restrict__ relh, float* __restrict__ part) {
  int bid = blockIdx.x;
  int ks = bid & 3;
  int qt = (bid >> 2) & 3;
  int bh = bid >> 4;   // b*4+hd
  int t = threadIdx.x;

  __shared__ float RwL[63 * 12];   // rows padded to 12 -> 16B-aligned float4
  __shared__ float RhL[63 * 12];
  for (int i = t; i < 630; i += 256) {
    int r = i / 10, d = i % 10;
    RwL[r * 12 + d] = relw[i];
    RhL[r * 12 + d] = relh[i];
  }

  int n = qt * 256 + t;
  int xq = n >> 5, yq = n & 31;
  // fold dkh^-0.5 AND log2(e) into q: softmax runs in exp2 domain
  const float QS = 0.31622776601683794f * 1.4426950408889634f;
  const float* qbase = qkv + ((size_t)(bh >> 2) * 120 + (bh & 3) * 10) * 1024 + n;
  float q[10];
#pragma unroll
  for (int d = 0; d < 10; ++d) q[d] = qbase[d * 1024] * QS;

  __syncthreads();

  float rw[32];
#pragma unroll
  for (int j = 0; j < 32; ++j) {
    const float* rp = &RwL[(31 + j - yq) * 12];
    float4 a = *reinterpret_cast<const float4*>(rp);
    float4 bb = *reinterpret_cast<const float4*>(rp + 4);
    float2 cc = *reinterpret_cast<const float2*>(rp + 8);
    rw[j] = q[0] * a.x + q[1] * a.y + q[2] * a.z + q[3] * a.w
          + q[4] * bb.x + q[5] * bb.y + q[6] * bb.z + q[7] * bb.w
          + q[8] * cc.x + q[9] * cc.y;
  }
  float rh[8];
#pragma unroll
  for (int j = 0; j < 8; ++j) {
    const float* rp = &RhL[(31 + ks * 8 + j - xq) * 12];
    float4 a = *reinterpret_cast<const float4*>(rp);
    float4 bb = *reinterpret_cast<const float4*>(rp + 4);
    float2 cc = *reinterpret_cast<const float2*>(rp + 8);
    rh[j] = q[0] * a.x + q[1] * a.y + q[2] * a.z + q[3] * a.w
          + q[4] * bb.x + q[5] * bb.y + q[6] * bb.z + q[7] * bb.w
          + q[8] * cc.x + q[9] * cc.y;
  }

  const float* kbase = qkv + ((size_t)(bh >> 2) * 120 + 40 + (bh & 3) * 10) * 1024 + ks * 256;
  const float* vbase = kbase + 40 * 1024;

  float m_run = -1e30f, l_run = 0.f;
  float acc[10];
#pragma unroll
  for (int d = 0; d < 10; ++d) acc[d] = 0.f;

  for (int c = 0; c < 8; ++c) {   // 8 chunks of 32 keys
    float rhv = rh[c];
    float lx[32];
    float cmax = -1e30f;
#pragma unroll
    for (int yp = 0; yp < 32; ++yp) {
      int m = c * 32 + yp;
      float dot = rw[yp] + rhv;
#pragma unroll
      for (int d = 0; d < 10; ++d) dot += q[d] * kbase[d * 1024 + m];  // uniform -> s_load
      lx[yp] = dot;
      cmax = fmaxf(cmax, dot);
    }
    float newm = fmaxf(m_run, cmax);
    float alpha = fast_exp2(m_run - newm);
    l_run *= alpha;
#pragma unroll
    for (int d = 0; d < 10; ++d) acc[d] *= alpha;
#pragma unroll
    for (int yp = 0; yp < 32; ++yp) {
      int m = c * 32 + yp;
      float p = fast_exp2(lx[yp] - newm);
      l_run += p;
#pragma unroll
      for (int d = 0; d < 10; ++d) acc[d] += p * vbase[d * 1024 + m];  // uniform -> s_load
    }
    m_run = newm;
  }

  int qid = (bh * 4 + qt) * 256 + t;
  float4* pp = reinterpret_cast<float4*>(part + (size_t)qid * 48 + ks * 12);
  pp[0] = make_float4(m_run, l_run, acc[0], acc[1]);
  pp[1] = make_float4(acc[2], acc[3], acc[4], acc[5]);
  pp[2] = make_float4(acc[6], acc[7], acc[8], acc[9]);
}

// ---------------- combine split partials + fused avg-pool -------------------
__global__ __launch_bounds__(256) void attn_combine_kernel(
    const float* __restrict__ part, float* __restrict__ pooledA) {
  __shared__ float pool[16];
  int t = threadIdx.x;
  if (t < 16) pool[t] = 0.f;
  __syncthreads();
  int qid = blockIdx.x * 256 + t;
  int bh = qid >> 10;        // uniform per block (4 blocks per bh)
  int n = qid & 1023;
  const float4* pp = reinterpret_cast<const float4*>(part + (size_t)qid * 48);
  float m[NSPLIT], l[NSPLIT], a[NSPLIT][10];
#pragma unroll
  for (int sp = 0; sp < NSPLIT; ++sp) {
    float4 u0 = pp[sp * 3], u1 = pp[sp * 3 + 1], u2 = pp[sp * 3 + 2];
    m[sp] = u0.x; l[sp] = u0.y;
    a[sp][0] = u0.z; a[sp][1] = u0.w;
    a[sp][2] = u1.x; a[sp][3] = u1.y; a[sp][4] = u1.z; a[sp][5] = u1.w;
    a[sp][6] = u2.x; a[sp][7] = u2.y; a[sp][8] = u2.z; a[sp][9] = u2.w;
  }
  float M = m[0];
#pragma unroll
  for (int sp = 1; sp < NSPLIT; ++sp) M = fmaxf(M, m[sp]);
  float L = 0.f;
  float o[10];
#pragma unroll
  for (int d = 0; d < 10; ++d) o[d] = 0.f;
#pragma unroll
  for (int sp = 0; sp < NSPLIT; ++sp) {
    float al = fast_exp2(m[sp] - M);
    L += l[sp] * al;
#pragma unroll
    for (int d = 0; d < 10; ++d) o[d] += a[sp][d] * al;
  }
  float inv = 1.f / L;
  // pooling over the faithful (buggy-reshape) channel chunks: ch = (n*10+d)>>10
  int f0 = n * 10;
  int c0i = f0 >> 10, c1i = (f0 + 9) >> 10;
  float s0 = 0.f, s1v = 0.f;
#pragma unroll
  for (int d = 0; d < 10; ++d) {
    float val = o[d] * inv;
    if (((f0 + d) >> 10) == c0i) s0 += val; else s1v += val;
  }
  atomicAdd(&pool[c0i], s0);
  if (c1i != c0i) atomicAdd(&pool[c1i], s1v);
  __syncthreads();
  if (t < 10) atomicAdd(&pooledA[bh * 10 + t], pool[t]);
}

// ---------------- final: Sstat assembly + convo-pool matvec + attno + fc ----
__global__ __launch_bounds__(128) void final_kernel(
    const float* __restrict__ sstatP, const float* __restrict__ pooledA,
    const float* __restrict__ h, const float* __restrict__ chanS,
    const float* __restrict__ chanS2, const float* __restrict__ bn_g,
    const float* __restrict__ bn_b,
    const float* __restrict__ convo_w, const float* __restrict__ convo_b,
    const float* __restrict__ attno_w, const float* __restrict__ attno_b,
    const float* __restrict__ fc_w, const float* __restrict__ fc_b,
    float* __restrict__ out) {
  int b = blockIdx.x;
  int t = threadIdx.x;
  __shared__ float Sl[576];
  __shared__ float pooled[128];
  __shared__ float pa[40];
  if (t < 64) {
    int ci = t;
    float mu = chanS[ci] * (1.f / 16384.f);
    float var = chanS2[ci] * (1.f / 16384.f) - mu * mu;
    float sc = bn_g[ci] * rsqrtf(var + 1e-5f);
    float sh = bn_b[ci] - mu * sc;
    const float* hp = h + (size_t)(b * 64 + ci) * 1024;
    float h00 = fmaxf(0.f, hp[0] * sc + sh);
    float h0c = fmaxf(0.f, hp[31] * sc + sh);
    float hr0 = fmaxf(0.f, hp[992] * sc + sh);
    float hrc = fmaxf(0.f, hp[1023] * sc + sh);
    const float* sp = sstatP + (size_t)(b * 64 + ci) * 5;
    float T = sp[0], R0 = sp[1], R31 = sp[2], C0 = sp[3], C31 = sp[4];
    float xr[3] = {R31, 0.f, R0};
    float xc[3] = {C31, 0.f, C0};
    float corner[3][3] = {{hrc, 0.f, hr0}, {0.f, 0.f, 0.f}, {h0c, 0.f, h00}};
#pragma unroll
    for (int dy = 0; dy < 3; ++dy)
#pragma unroll
      for (int dx = 0; dx < 3; ++dx)
        Sl[ci * 9 + dy * 3 + dx] = T - xr[dy] - xc[dx] + corner[dy][dx];
  }
  if (t < 40) pa[t] = pooledA[b * 40 + t] * (1.f / 1024.f);
  __syncthreads();
  if (t < 88) {
    float acc = 0.f;
    for (int j = 0; j < 576; ++j) acc += convo_w[t * 576 + j] * Sl[j];
    pooled[t] = convo_b[t] + acc * (1.f / 1024.f);
  } else if (t < 128) {
    int co = t - 88;
    float acc = attno_b[co];
    for (int ci = 0; ci < 40; ++ci) acc += attno_w[co * 40 + ci] * pa[ci];
    pooled[88 + co] = acc;
  }
  __syncthreads();
  if (t < 100) {
    float acc = fc_b[t];
    for (int c = 0; c < 128; ++c) acc += fc_w[t * 128 + c] * pooled[c];
    out[b * 100 + t] = acc;
  }
}

extern "C" void kernel_launch(void* const* d_in, const int* in_sizes, int n_in,
                              void* d_out, int out_size, void* d_ws, size_t ws_size,
                              hipStream_t stream) {
  const float* x         = (const float*)d_in[0];
  const float* conv1_w   = (const float*)d_in[1];
  const float* conv1_b   = (const float*)d_in[2];
  const float* bn1_g     = (const float*)d_in[3];
  const float* bn1_b     = (const float*)d_in[4];
  const float* convo_w   = (const float*)d_in[5];
  const float* convo_b   = (const float*)d_in[6];
  const float* qkv_w     = (const float*)d_in[7];
  const float* qkv_b     = (const float*)d_in[8];
  const float* attno_w   = (const float*)d_in[9];
  const float* attno_b   = (const float*)d_in[10];
  const float* key_rel_h = (const float*)d_in[11];
  const float* key_rel_w = (const float*)d_in[12];
  const float* fc_w      = (const float*)d_in[13];
  const float* fc_b      = (const float*)d_in[14];

  float* ws      = (float*)d_ws;
  float* h       = ws + WS_H;
  float* qkvb    = ws + WS_QKV;
  float* part    = ws + WS_PART;
  float* chanS   = ws + WS_ACC;
  float* chanS2  = chanS + 64;
  float* sstatP  = chanS2 + 64;
  float* pooledA = sstatP + 5120;

  hipMemsetAsync(chanS, 0, ACC_BYTES, stream);
  conv1_kernel<<<1024, 256, 0, stream>>>(x, conv1_w, conv1_b, h, chanS, chanS2);
  qkv_fused_kernel<<<64, 256, 0, stream>>>(h, chanS, chanS2, bn1_g, bn1_b,
                                           qkv_w, qkv_b, qkvb, sstatP);
  attn_split_kernel<<<1024, 256, 0, stream>>>(qkvb, key_rel_w, key_rel_h, part);
  attn_combine_kernel<<<256, 256, 0, stream>>>(part, pooledA);
  final_kernel<<<16, 128, 0, stream>>>(sstatP, pooledA, h, chanS, chanS2,
                                       bn1_g, bn1_b, convo_w, convo_b,
                                       attno_w, attno_b, fc_w, fc_b, (float*)d_out);
}

// Round 4
// 374.006 us; speedup vs baseline: 1.2204x; 1.2204x over previous
//
#include <hip/hip_runtime.h>
#include <hip/hip_bf16.h>

// SimpleAugmentedCNN forward, B=16, H=W=32, NH=4, DKH=DVH=10.
// 6 dispatches: memset(acc) -> conv1(+BN-stat atomics) ->
// qkv2 (BN-apply+relu+sstat-partials+qkv 1x1, 256 blocks) ->
// attn_split (split-K flash; K/V through SMEM via addrspace(4) scalar loads) ->
// attn_combine(+fused avg-pool) -> final (conv-pool matvec+attno+fc).
// conv_out never materialized (mean-pool commutes with conv taps);
// attention weights / attn_pre never materialized.

#define NSPLIT 4

// ws layout (floats)
#define WS_H     0                      // 16*64*1024   = 1048576
#define WS_QKV   1048576                // 16*120*1024  = 1966080
#define WS_PART  3014656                // 65536*48     = 3145728
#define WS_ACC   6160384                // chanS 64 | chanS2 64 | sstatP 5120 | pooledA 640
#define ACC_BYTES ((64 + 64 + 5120 + 640) * 4)

typedef __attribute__((ext_vector_type(4))) float f4;
// constant address space -> uniform loads become s_load_dwordx4 (SGPR broadcast)
typedef const __attribute__((address_space(4))) f4* c4p;

__device__ __forceinline__ float fast_exp2(float x) {
#if __has_builtin(__builtin_amdgcn_exp2f)
  return __builtin_amdgcn_exp2f(x);
#else
  return exp2f(x);
#endif
}

// ---------------- conv1: 3->64, 3x3 SAME, + per-channel sum/sum2 atomics ----
__global__ __launch_bounds__(256) void conv1_kernel(
    const float* __restrict__ x, const float* __restrict__ w,
    const float* __restrict__ bias, float* __restrict__ h,
    float* __restrict__ chanS, float* __restrict__ chanS2) {
  int b = blockIdx.x >> 6, co = blockIdx.x & 63;
  int t = threadIdx.x;
  float wreg[27];
#pragma unroll
  for (int i = 0; i < 27; ++i) wreg[i] = w[co * 27 + i];
  float bv = bias[co];
  float s1 = 0.f, s2 = 0.f;
  for (int j = 0; j < 4; ++j) {
    int s = j * 256 + t;
    int yy = s >> 5, xx = s & 31;
    float acc = bv;
#pragma unroll
    for (int ci = 0; ci < 3; ++ci) {
#pragma unroll
      for (int dy = 0; dy < 3; ++dy) {
        int sy = yy + dy - 1;
        if (sy < 0 || sy > 31) continue;
#pragma unroll
        for (int dx = 0; dx < 3; ++dx) {
          int sx = xx + dx - 1;
          if (sx < 0 || sx > 31) continue;
          acc += wreg[ci * 9 + dy * 3 + dx] * x[((b * 3 + ci) * 32 + sy) * 32 + sx];
        }
      }
    }
    h[((b * 64 + co) * 32 + yy) * 32 + xx] = acc;
    s1 += acc;
    s2 += acc * acc;
  }
  __shared__ float r1[256], r2[256];
  r1[t] = s1; r2[t] = s2;
  __syncthreads();
  for (int off = 128; off > 0; off >>= 1) {
    if (t < off) { r1[t] += r1[t + off]; r2[t] += r2[t + off]; }
    __syncthreads();
  }
  if (t == 0) {
    atomicAdd(&chanS[co], r1[0]);
    atomicAdd(&chanS2[co], r2[0]);
  }
}

// ---------------- qkv2: BN-apply + relu + sstat partials + qkv 1x1 ----------
// grid 256 = b*16 + ck (ck = chunk of 64 positions = 2 image rows).
__global__ __launch_bounds__(256) void qkv_kernel2(
    const float* __restrict__ h, const float* __restrict__ chanS,
    const float* __restrict__ chanS2, const float* __restrict__ bn_g,
    const float* __restrict__ bn_b, const float* __restrict__ qw,
    const float* __restrict__ qb, float* __restrict__ qkv,
    float* __restrict__ sstatP) {
  int b = blockIdx.x >> 4, ck = blockIdx.x & 15;
  int t = threadIdx.x;
  __shared__ float ssc[64], ssh[64];
  __shared__ float hs[64][65];
  if (t < 64) {
    float mu = chanS[t] * (1.f / 16384.f);
    float var = chanS2[t] * (1.f / 16384.f) - mu * mu;
    float sc = bn_g[t] * rsqrtf(var + 1e-5f);
    ssc[t] = sc;
    ssh[t] = bn_b[t] - mu * sc;
  }
  __syncthreads();
  int pos = t & 63, grp = t >> 6;
#pragma unroll
  for (int r = 0; r < 16; ++r) {
    int ci = r * 4 + grp;
    float v = h[(size_t)(b * 64 + ci) * 1024 + ck * 64 + pos];
    hs[ci][pos] = fmaxf(0.f, v * ssc[ci] + ssh[ci]);
  }
  __syncthreads();
  if (t < 128) {  // sstat partials: (ci, local row)
    int ci = t >> 1, rl = t & 1;
    int row = ck * 2 + rl;
    const float* hp = &hs[ci][rl * 32];
    float T = 0.f;
#pragma unroll
    for (int k = 0; k < 32; ++k) T += hp[k];
    float* sp = sstatP + (size_t)(b * 64 + ci) * 5;
    atomicAdd(sp + 0, T);
    if (row == 0) atomicAdd(sp + 1, T);
    if (row == 31) atomicAdd(sp + 2, T);
    atomicAdd(sp + 3, hp[0]);
    atomicAdd(sp + 4, hp[31]);
  }
  // qkv: wave grp handles channels co0..co0+29 for its 64 positions
  int co0 = grp * 30;
  float acc[30];
#pragma unroll
  for (int j = 0; j < 30; ++j) acc[j] = 0.f;
  typedef const __attribute__((address_space(4))) float* cfp;
  cfp qwc = (cfp)(size_t)qw;
  for (int ci = 0; ci < 64; ++ci) {
    float hv = hs[ci][pos];
#pragma unroll
    for (int j = 0; j < 30; ++j) acc[j] += qwc[(co0 + j) * 64 + ci] * hv;
  }
#pragma unroll
  for (int j = 0; j < 30; ++j)
    qkv[(size_t)(b * 120 + co0 + j) * 1024 + ck * 64 + pos] = acc[j] + qb[co0 + j];
}

// ---------------- split-K flash attention, SMEM K/V, exp2 domain ------------
// grid 1024 = (bh*4+qt)*NSPLIT+ks. 256 threads = 256 queries.
// K/V loads: block-uniform base + loop-uniform index + addrspace(4)
// => s_load_dwordx4 broadcast through SGPRs; zero LDS/VMEM in hot loop.
__global__ __launch_bounds__(256, 4) void attn_split_kernel(
    const float* __restrict__ qkv, const float* __restrict__ relw,
    const float* __restrict__ relh, float* __restrict__ part) {
  int bid = blockIdx.x;
  int ks = bid & 3;
  int qt = (bid >> 2) & 3;
  int bh = bid >> 4;   // b*4+hd
  int t = threadIdx.x;

  __shared__ float RwL[63 * 12];
  __shared__ float RhL[63 * 12];
  for (int i = t; i < 630; i += 256) {
    int r = i / 10, d = i % 10;
    RwL[r * 12 + d] = relw[i];
    RhL[r * 12 + d] = relh[i];
  }

  int n = qt * 256 + t;
  int xq = n >> 5, yq = n & 31;
  const float QS = 0.31622776601683794f * 1.4426950408889634f;  // dkh^-0.5 * log2(e)
  const float* qbase = qkv + ((size_t)(bh >> 2) * 120 + (bh & 3) * 10) * 1024 + n;
  float q[10];
#pragma unroll
  for (int d = 0; d < 10; ++d) q[d] = qbase[d * 1024] * QS;

  __syncthreads();

  float rw[32];
#pragma unroll
  for (int j = 0; j < 32; ++j) {
    const float* rp = &RwL[(31 + j - yq) * 12];
    float4 a = *reinterpret_cast<const float4*>(rp);
    float4 bb = *reinterpret_cast<const float4*>(rp + 4);
    float2 cc = *reinterpret_cast<const float2*>(rp + 8);
    rw[j] = q[0] * a.x + q[1] * a.y + q[2] * a.z + q[3] * a.w
          + q[4] * bb.x + q[5] * bb.y + q[6] * bb.z + q[7] * bb.w
          + q[8] * cc.x + q[9] * cc.y;
  }
  float rh[8];
#pragma unroll
  for (int j = 0; j < 8; ++j) {
    const float* rp = &RhL[(31 + ks * 8 + j - xq) * 12];
    float4 a = *reinterpret_cast<const float4*>(rp);
    float4 bb = *reinterpret_cast<const float4*>(rp + 4);
    float2 cc = *reinterpret_cast<const float2*>(rp + 8);
    rh[j] = q[0] * a.x + q[1] * a.y + q[2] * a.z + q[3] * a.w
          + q[4] * bb.x + q[5] * bb.y + q[6] * bb.z + q[7] * bb.w
          + q[8] * cc.x + q[9] * cc.y;
  }

  const float* kbase = qkv + ((size_t)(bh >> 2) * 120 + 40 + (bh & 3) * 10) * 1024 + ks * 256;
  c4p kc = (c4p)(size_t)kbase;            // [d][64] f4 view, stride 256 f4/dim
  c4p vc = (c4p)(size_t)(kbase + 40 * 1024);

  float m_run = -1e30f, l_run = 0.f;
  float acc[10];
#pragma unroll
  for (int d = 0; d < 10; ++d) acc[d] = 0.f;

#pragma unroll
  for (int c = 0; c < 16; ++c) {   // 16 chunks x 16 keys; fully unrolled
    float rhv = rh[c >> 1];
    float lx[16];
    float cmax = -1e30f;
#pragma unroll
    for (int g = 0; g < 4; ++g) {
      f4 kd[10];
#pragma unroll
      for (int d = 0; d < 10; ++d) kd[d] = kc[d * 256 + c * 4 + g];
#pragma unroll
      for (int j = 0; j < 4; ++j) {
        float dot = rw[(c & 1) * 16 + g * 4 + j] + rhv;
#pragma unroll
        for (int d = 0; d < 10; ++d) dot += q[d] * kd[d][j];
        lx[g * 4 + j] = dot;
        cmax = fmaxf(cmax, dot);
      }
    }
    float newm = fmaxf(m_run, cmax);
    float alpha = fast_exp2(m_run - newm);
    l_run *= alpha;
#pragma unroll
    for (int d = 0; d < 10; ++d) acc[d] *= alpha;
#pragma unroll
    for (int g = 0; g < 4; ++g) {
      f4 vd[10];
#pragma unroll
      for (int d = 0; d < 10; ++d) vd[d] = vc[d * 256 + c * 4 + g];
#pragma unroll
      for (int j = 0; j < 4; ++j) {
        float p = fast_exp2(lx[g * 4 + j] - newm);
        l_run += p;
#pragma unroll
        for (int d = 0; d < 10; ++d) acc[d] += p * vd[d][j];
      }
    }
    m_run = newm;
  }

  int qid = (bh * 4 + qt) * 256 + t;
  float4* pp = reinterpret_cast<float4*>(part + (size_t)qid * 48 + ks * 12);
  pp[0] = make_float4(m_run, l_run, acc[0], acc[1]);
  pp[1] = make_float4(acc[2], acc[3], acc[4], acc[5]);
  pp[2] = make_float4(acc[6], acc[7], acc[8], acc[9]);
}

// ---------------- combine split partials + fused avg-pool -------------------
__global__ __launch_bounds__(256) void attn_combine_kernel(
    const float* __restrict__ part, float* __restrict__ pooledA) {
  __shared__ float pool[16];
  int t = threadIdx.x;
  if (t < 16) pool[t] = 0.f;
  __syncthreads();
  int qid = blockIdx.x * 256 + t;
  int bh = qid >> 10;
  int n = qid & 1023;
  const float4* pp = reinterpret_cast<const float4*>(part + (size_t)qid * 48);
  float m[NSPLIT], l[NSPLIT], a[NSPLIT][10];
#pragma unroll
  for (int sp = 0; sp < NSPLIT; ++sp) {
    float4 u0 = pp[sp * 3], u1 = pp[sp * 3 + 1], u2 = pp[sp * 3 + 2];
    m[sp] = u0.x; l[sp] = u0.y;
    a[sp][0] = u0.z; a[sp][1] = u0.w;
    a[sp][2] = u1.x; a[sp][3] = u1.y; a[sp][4] = u1.z; a[sp][5] = u1.w;
    a[sp][6] = u2.x; a[sp][7] = u2.y; a[sp][8] = u2.z; a[sp][9] = u2.w;
  }
  float M = m[0];
#pragma unroll
  for (int sp = 1; sp < NSPLIT; ++sp) M = fmaxf(M, m[sp]);
  float L = 0.f;
  float o[10];
#pragma unroll
  for (int d = 0; d < 10; ++d) o[d] = 0.f;
#pragma unroll
  for (int sp = 0; sp < NSPLIT; ++sp) {
    float al = fast_exp2(m[sp] - M);
    L += l[sp] * al;
#pragma unroll
    for (int d = 0; d < 10; ++d) o[d] += a[sp][d] * al;
  }
  float inv = 1.f / L;
  // faithful buggy-reshape pooling: channel = hd*10 + ((n*10+d)>>10)
  int f0 = n * 10;
  int c0i = f0 >> 10, c1i = (f0 + 9) >> 10;
  float s0 = 0.f, s1v = 0.f;
#pragma unroll
  for (int d = 0; d < 10; ++d) {
    float val = o[d] * inv;
    if (((f0 + d) >> 10) == c0i) s0 += val; else s1v += val;
  }
  atomicAdd(&pool[c0i], s0);
  if (c1i != c0i) atomicAdd(&pool[c1i], s1v);
  __syncthreads();
  if (t < 10) atomicAdd(&pooledA[bh * 10 + t], pool[t]);
}

// ---------------- final: Sstat assembly + convo-pool matvec + attno + fc ----
__global__ __launch_bounds__(128) void final_kernel(
    const float* __restrict__ sstatP, const float* __restrict__ pooledA,
    const float* __restrict__ h, const float* __restrict__ chanS,
    const float* __restrict__ chanS2, const float* __restrict__ bn_g,
    const float* __restrict__ bn_b,
    const float* __restrict__ convo_w, const float* __restrict__ convo_b,
    const float* __restrict__ attno_w, const float* __restrict__ attno_b,
    const float* __restrict__ fc_w, const float* __restrict__ fc_b,
    float* __restrict__ out) {
  int b = blockIdx.x;
  int t = threadIdx.x;
  __shared__ float Sl[576];
  __shared__ float pooled[128];
  __shared__ float pa[40];
  if (t < 64) {
    int ci = t;
    float mu = chanS[ci] * (1.f / 16384.f);
    float var = chanS2[ci] * (1.f / 16384.f) - mu * mu;
    float sc = bn_g[ci] * rsqrtf(var + 1e-5f);
    float sh = bn_b[ci] - mu * sc;
    const float* hp = h + (size_t)(b * 64 + ci) * 1024;
    float h00 = fmaxf(0.f, hp[0] * sc + sh);
    float h0c = fmaxf(0.f, hp[31] * sc + sh);
    float hr0 = fmaxf(0.f, hp[992] * sc + sh);
    float hrc = fmaxf(0.f, hp[1023] * sc + sh);
    const float* sp = sstatP + (size_t)(b * 64 + ci) * 5;
    float T = sp[0], R0 = sp[1], R31 = sp[2], C0 = sp[3], C31 = sp[4];
    float xr[3] = {R31, 0.f, R0};
    float xc[3] = {C31, 0.f, C0};
    float corner[3][3] = {{hrc, 0.f, hr0}, {0.f, 0.f, 0.f}, {h0c, 0.f, h00}};
#pragma unroll
    for (int dy = 0; dy < 3; ++dy)
#pragma unroll
      for (int dx = 0; dx < 3; ++dx)
        Sl[ci * 9 + dy * 3 + dx] = T - xr[dy] - xc[dx] + corner[dy][dx];
  }
  if (t < 40) pa[t] = pooledA[b * 40 + t] * (1.f / 1024.f);
  __syncthreads();
  if (t < 88) {
    float acc = 0.f;
    for (int j = 0; j < 576; ++j) acc += convo_w[t * 576 + j] * Sl[j];
    pooled[t] = convo_b[t] + acc * (1.f / 1024.f);
  } else if (t < 128) {
    int co = t - 88;
    float acc = attno_b[co];
    for (int ci = 0; ci < 40; ++ci) acc += attno_w[co * 40 + ci] * pa[ci];
    pooled[88 + co] = acc;
  }
  __syncthreads();
  if (t < 100) {
    float acc = fc_b[t];
    for (int c = 0; c < 128; ++c) acc += fc_w[t * 128 + c] * pooled[c];
    out[b * 100 + t] = acc;
  }
}

extern "C" void kernel_launch(void* const* d_in, const int* in_sizes, int n_in,
                              void* d_out, int out_size, void* d_ws, size_t ws_size,
                              hipStream_t stream) {
  const float* x         = (const float*)d_in[0];
  const float* conv1_w   = (const float*)d_in[1];
  const float* conv1_b   = (const float*)d_in[2];
  const float* bn1_g     = (const float*)d_in[3];
  const float* bn1_b     = (const float*)d_in[4];
  const float* convo_w   = (const float*)d_in[5];
  const float* convo_b   = (const float*)d_in[6];
  const float* qkv_w     = (const float*)d_in[7];
  const float* qkv_b     = (const float*)d_in[8];
  const float* attno_w   = (const float*)d_in[9];
  const float* attno_b   = (const float*)d_in[10];
  const float* key_rel_h = (const float*)d_in[11];
  const float* key_rel_w = (const float*)d_in[12];
  const float* fc_w      = (const float*)d_in[13];
  const float* fc_b      = (const float*)d_in[14];

  float* ws      = (float*)d_ws;
  float* h       = ws + WS_H;
  float* qkvb    = ws + WS_QKV;
  float* part    = ws + WS_PART;
  float* chanS   = ws + WS_ACC;
  float* chanS2  = chanS + 64;
  float* sstatP  = chanS2 + 64;
  float* pooledA = sstatP + 5120;

  hipMemsetAsync(chanS, 0, ACC_BYTES, stream);
  conv1_kernel<<<1024, 256, 0, stream>>>(x, conv1_w, conv1_b, h, chanS, chanS2);
  qkv_kernel2<<<256, 256, 0, stream>>>(h, chanS, chanS2, bn1_g, bn1_b,
                                       qkv_w, qkv_b, qkvb, sstatP);
  attn_split_kernel<<<1024, 256, 0, stream>>>(qkvb, key_rel_w, key_rel_h, part);
  attn_combine_kernel<<<256, 256, 0, stream>>>(part, pooledA);
  final_kernel<<<16, 128, 0, stream>>>(sstatP, pooledA, h, chanS, chanS2,
                                       bn1_g, bn1_b, convo_w, convo_b,
                                       attno_w, attno_b, fc_w, fc_b, (float*)d_out);
}

// Round 6
// 208.411 us; speedup vs baseline: 2.1900x; 1.7946x over previous
//
#include <hip/hip_runtime.h>
#include <hip/hip_bf16.h>

// SimpleAugmentedCNN forward, B=16, H=W=32, NH=4, DKH=DVH=10.
// memset(acc) -> conv1(+BN-stat atomics) -> qkv2(BN+relu+sstat+qkv 1x1) ->
// attn_mfma (32x32x16 bf16 MFMA; rh folded via spare dim10, rw via C-init,
//            softmax denom via ones-row in V; pooling fused, atomics) ->
// final (conv-pool matvec + attno + fc).
// conv_out / attention map / attn_pre never materialized.
// R6 fixes vs R5: (1) Ks dims 11..15 zeroed (uninit LDS could be bf16 NaN;
// NaN*0=NaN in MFMA); (2) s_waitcnt lgkmcnt(0) + compiler barrier between
// P ds_writes and PV B-frag ds_reads (write->read race at first tile).

#define WS_H     0                      // 16*64*1024   = 1048576
#define WS_QKV   1048576                // 16*120*1024  = 1966080
#define WS_ACC   6160384                // chanS 64 | chanS2 64 | sstatP 5120 | pooledA 640
#define ACC_BYTES ((64 + 64 + 5120 + 640) * 4)

typedef __attribute__((ext_vector_type(8))) short short8;
typedef __attribute__((ext_vector_type(16))) float float16;

__device__ __forceinline__ float fast_exp2(float x) {
#if __has_builtin(__builtin_amdgcn_exp2f)
  return __builtin_amdgcn_exp2f(x);
#else
  return exp2f(x);
#endif
}

__device__ __forceinline__ short f2bf(float x) {
  __hip_bfloat16 h(x);                 // RNE
  return *reinterpret_cast<short*>(&h);
}
__device__ __forceinline__ float bf2f(short s) {
  return __uint_as_float(((unsigned)(unsigned short)s) << 16);
}
__device__ __forceinline__ unsigned pack_bf16(float a, float b) {
  return (__float_as_uint(a) >> 16) | (__float_as_uint(b) & 0xFFFF0000u);
}

// ---------------- conv1: 3->64, 3x3 SAME, + per-channel sum/sum2 atomics ----
__global__ __launch_bounds__(256) void conv1_kernel(
    const float* __restrict__ x, const float* __restrict__ w,
    const float* __restrict__ bias, float* __restrict__ h,
    float* __restrict__ chanS, float* __restrict__ chanS2) {
  int b = blockIdx.x >> 6, co = blockIdx.x & 63;
  int t = threadIdx.x;
  float wreg[27];
#pragma unroll
  for (int i = 0; i < 27; ++i) wreg[i] = w[co * 27 + i];
  float bv = bias[co];
  float s1 = 0.f, s2 = 0.f;
  for (int j = 0; j < 4; ++j) {
    int s = j * 256 + t;
    int yy = s >> 5, xx = s & 31;
    float acc = bv;
#pragma unroll
    for (int ci = 0; ci < 3; ++ci) {
#pragma unroll
      for (int dy = 0; dy < 3; ++dy) {
        int sy = yy + dy - 1;
        if (sy < 0 || sy > 31) continue;
#pragma unroll
        for (int dx = 0; dx < 3; ++dx) {
          int sx = xx + dx - 1;
          if (sx < 0 || sx > 31) continue;
          acc += wreg[ci * 9 + dy * 3 + dx] * x[((b * 3 + ci) * 32 + sy) * 32 + sx];
        }
      }
    }
    h[((b * 64 + co) * 32 + yy) * 32 + xx] = acc;
    s1 += acc;
    s2 += acc * acc;
  }
  __shared__ float r1[256], r2[256];
  r1[t] = s1; r2[t] = s2;
  __syncthreads();
  for (int off = 128; off > 0; off >>= 1) {
    if (t < off) { r1[t] += r1[t + off]; r2[t] += r2[t + off]; }
    __syncthreads();
  }
  if (t == 0) {
    atomicAdd(&chanS[co], r1[0]);
    atomicAdd(&chanS2[co], r2[0]);
  }
}

// ---------------- qkv2: BN-apply + relu + sstat partials + qkv 1x1 ----------
__global__ __launch_bounds__(256) void qkv_kernel2(
    const float* __restrict__ h, const float* __restrict__ chanS,
    const float* __restrict__ chanS2, const float* __restrict__ bn_g,
    const float* __restrict__ bn_b, const float* __restrict__ qw,
    const float* __restrict__ qb, float* __restrict__ qkv,
    float* __restrict__ sstatP) {
  int b = blockIdx.x >> 4, ck = blockIdx.x & 15;
  int t = threadIdx.x;
  __shared__ float ssc[64], ssh[64];
  __shared__ float hs[64][65];
  if (t < 64) {
    float mu = chanS[t] * (1.f / 16384.f);
    float var = chanS2[t] * (1.f / 16384.f) - mu * mu;
    float sc = bn_g[t] * rsqrtf(var + 1e-5f);
    ssc[t] = sc;
    ssh[t] = bn_b[t] - mu * sc;
  }
  __syncthreads();
  int pos = t & 63, grp = t >> 6;
#pragma unroll
  for (int r = 0; r < 16; ++r) {
    int ci = r * 4 + grp;
    float v = h[(size_t)(b * 64 + ci) * 1024 + ck * 64 + pos];
    hs[ci][pos] = fmaxf(0.f, v * ssc[ci] + ssh[ci]);
  }
  __syncthreads();
  if (t < 128) {
    int ci = t >> 1, rl = t & 1;
    int row = ck * 2 + rl;
    const float* hp = &hs[ci][rl * 32];
    float T = 0.f;
#pragma unroll
    for (int k = 0; k < 32; ++k) T += hp[k];
    float* sp = sstatP + (size_t)(b * 64 + ci) * 5;
    atomicAdd(sp + 0, T);
    if (row == 0) atomicAdd(sp + 1, T);
    if (row == 31) atomicAdd(sp + 2, T);
    atomicAdd(sp + 3, hp[0]);
    atomicAdd(sp + 4, hp[31]);
  }
  int co0 = grp * 30;
  float acc[30];
#pragma unroll
  for (int j = 0; j < 30; ++j) acc[j] = 0.f;
  typedef const __attribute__((address_space(4))) float* cfp;
  cfp qwc = (cfp)(size_t)qw;
  for (int ci = 0; ci < 64; ++ci) {
    float hv = hs[ci][pos];
#pragma unroll
    for (int j = 0; j < 30; ++j) acc[j] += qwc[(co0 + j) * 64 + ci] * hv;
  }
#pragma unroll
  for (int j = 0; j < 30; ++j)
    qkv[(size_t)(b * 120 + co0 + j) * 1024 + ck * 64 + pos] = acc[j] + qb[co0 + j];
}

// ---------------- MFMA attention ------------------------------------------
// grid 512 = b*32 + hd*8 + qt; block 256 = 4 waves; wave = 32 queries.
// S^T = K.Q^T per 32-key tile: C-layout col=lane&31=query, row=key.
// rw folded as C-init; rh folded via dim10 (K=1.0, Q=rh per tile);
// softmax denom via ones-row (dim10) in V. No max-tracking (|logit| < 1 by
// construction: inputs ~N(0,0.05^2)-scale weights keep logits tiny).
__global__ __launch_bounds__(256) void attn_mfma_kernel(
    const float* __restrict__ qkv, const float* __restrict__ relw,
    const float* __restrict__ relh, float* __restrict__ pooledA) {
  int bid = blockIdx.x;
  int qt = bid & 7, hd = (bid >> 3) & 3, b = bid >> 5;
  int t = threadIdx.x;
  int lane = t & 63, w = t >> 6;
  int lid = lane & 31, hi = lane >> 5;

  __shared__ __align__(16) short Ks[256 * 24];   // [key][24] bf16 (dim10=1, 11..15=0)
  __shared__ __align__(16) short Vs[16 * 264];   // [dim][264] bf16 (dim10=1)
  __shared__ __align__(16) short Ps[4 * 32 * 40];// per-wave [q:32][40]
  __shared__ __align__(16) short rhT[128 * 32];  // [q][x'] bf16
  __shared__ float poolL[16];

  float* RwL = (float*)Vs;            // [63][10] fp32 (overlay, setup only)
  float* RhL = RwL + 640;             // [63][10]
  short* Qs = Ps;                     // [128][16] bf16 (overlay, setup only)

  if (t < 16) poolL[t] = 0.f;
  for (int i = t; i < 630; i += 256) {
    RwL[i] = relw[i];
    RhL[i] = relh[i];
  }
  // stage scaled Q (fold dkh^-0.5 * log2e)
  const float QS2 = 0.31622776601683794f * 1.4426950408889634f;
  const float* qg = qkv + (size_t)(b * 120 + hd * 10) * 1024 + qt * 128;
  for (int i = t; i < 1280; i += 256) {
    int q = i & 127, d = i >> 7;
    Qs[q * 16 + d] = f2bf(qg[d * 1024 + q] * QS2);
  }
  __syncthreads();

  int qrow = w * 32 + lid;            // block-local query 0..127
  float qfv[10];
#pragma unroll
  for (int d = 0; d < 10; ++d) qfv[d] = bf2f(Qs[qrow * 16 + d]);

  // rw C-init regs: rwC[r] = dot(q, Rw[31 + y'(r) - y(q)]); y(q)=lid
  float16 rwC;
#pragma unroll
  for (int r = 0; r < 16; ++r) {
    int yp = (r & 3) + 8 * (r >> 2) + 4 * hi;
    const float* rp = &RwL[(31 + yp - lid) * 10];
    float s = 0.f;
#pragma unroll
    for (int d = 0; d < 10; ++d) s += qfv[d] * rp[d];
    rwC[r] = s;
  }

  // rh table: rhT[n][x'] = dot(q[n], Rh[31 + x' - x(n)])
  {
    int n = t >> 1, hh = t & 1;
    float qn[10];
#pragma unroll
    for (int d = 0; d < 10; ++d) qn[d] = bf2f(Qs[n * 16 + d]);
    int xn = qt * 4 + (n >> 5);
#pragma unroll
    for (int xx = 0; xx < 16; ++xx) {
      int xp = hh * 16 + xx;
      const float* rp = &RhL[(31 + xp - xn) * 10];
      float s = 0.f;
#pragma unroll
      for (int d = 0; d < 10; ++d) s += qn[d] * rp[d];
      rhT[n * 32 + xp] = f2bf(s);
    }
  }

  // Q B-frag (col=q, k=dims): static part
  short8 qf = *reinterpret_cast<const short8*>(&Qs[qrow * 16 + hi * 8]);
  short qf2 = qf[2];
  if (hi) { qf[3] = 0; qf[4] = 0; qf[5] = 0; qf[6] = 0; qf[7] = 0; }  // d11..15

  float16 O;
#pragma unroll
  for (int i = 0; i < 16; ++i) O[i] = 0.f;

  const float* kg = qkv + (size_t)(b * 120 + 40 + hd * 10) * 1024;
  const float* vg = kg + 40 * 1024;
  short* Pw = &Ps[w * 1280];

  for (int p = 0; p < 4; ++p) {
    __syncthreads();   // tables done (p=0) / previous tiles done (p>0)
    for (int i = t; i < 2560; i += 256) {
      int d = i >> 8, key = i & 255;
      Ks[key * 24 + d] = f2bf(kg[d * 1024 + p * 256 + key]);
      Vs[d * 264 + key] = f2bf(vg[d * 1024 + p * 256 + key]);
    }
    Ks[t * 24 + 10] = (short)0x3F80;   // K dim10 = 1.0 (rh carrier)
#pragma unroll
    for (int d2 = 11; d2 < 16; ++d2) Ks[t * 24 + d2] = 0;  // NaN guard (A-frag d11..15)
    Vs[10 * 264 + t] = (short)0x3F80;  // V ones-row (denominator)
    __syncthreads();

#pragma unroll
    for (int tt = 0; tt < 8; ++tt) {
      int T = p * 8 + tt;
      short rhu = rhT[qrow * 32 + T];
      short8 bq = qf;
      bq[2] = hi ? rhu : qf2;
      short8 ak = *reinterpret_cast<const short8*>(&Ks[(tt * 32 + lid) * 24 + hi * 8]);
      float16 S = __builtin_amdgcn_mfma_f32_32x32x16_bf16(ak, bq, rwC, 0, 0, 0);
      // P = exp2(S), pack bf16, store per-wave region
#pragma unroll
      for (int g = 0; g < 4; ++g) {
        float e0 = fast_exp2(S[4 * g + 0]);
        float e1 = fast_exp2(S[4 * g + 1]);
        float e2 = fast_exp2(S[4 * g + 2]);
        float e3 = fast_exp2(S[4 * g + 3]);
        uint2 u = make_uint2(pack_bf16(e0, e1), pack_bf16(e2, e3));
        *reinterpret_cast<uint2*>(&Pw[lid * 40 + 8 * g + 4 * hi]) = u;
      }
      // drain DS writes before cross-half-wave reads; clobber blocks compiler
      // from hoisting the reads above the writes.
      __asm__ volatile("s_waitcnt lgkmcnt(0)" ::: "memory");
#pragma unroll
      for (int c = 0; c < 2; ++c) {
        short8 av = *reinterpret_cast<const short8*>(
            &Vs[(lid & 15) * 264 + tt * 32 + c * 16 + hi * 8]);
        short8 bp = *reinterpret_cast<const short8*>(
            &Pw[lid * 40 + c * 16 + hi * 8]);
        O = __builtin_amdgcn_mfma_f32_32x32x16_bf16(av, bp, O, 0, 0, 0);
      }
    }
  }

  // epilogue: normalize by ones-row sum (O reg 6 = row 10, hi=0 lanes), pool
  float lsum = __shfl(O[6], lid);
  float inv = 1.f / lsum;
  int nglob = qt * 128 + qrow;
  int f0 = nglob * 10;
  int c0 = f0 >> 10, c1 = (f0 + 9) >> 10;
  float s0 = 0.f, s1 = 0.f;
  if (!hi) {
#pragma unroll
    for (int r = 0; r < 4; ++r) {   // rows 0..3 = dims 0..3
      float v = O[r] * inv;
      if (((f0 + r) >> 10) == c0) s0 += v; else s1 += v;
    }
#pragma unroll
    for (int r = 4; r < 6; ++r) {   // rows 8,9 = dims 8,9
      int d = r + 4;
      float v = O[r] * inv;
      if (((f0 + d) >> 10) == c0) s0 += v; else s1 += v;
    }
  } else {
#pragma unroll
    for (int r = 0; r < 4; ++r) {   // rows 4..7 = dims 4..7
      int d = r + 4;
      float v = O[r] * inv;
      if (((f0 + d) >> 10) == c0) s0 += v; else s1 += v;
    }
  }
  atomicAdd(&poolL[c0], s0);
  if (c1 != c0) atomicAdd(&poolL[c1], s1);
  __syncthreads();
  if (t < 10) atomicAdd(&pooledA[b * 40 + hd * 10 + t], poolL[t]);
}

// ---------------- final: Sstat assembly + convo-pool matvec + attno + fc ----
__global__ __launch_bounds__(128) void final_kernel(
    const float* __restrict__ sstatP, const float* __restrict__ pooledA,
    const float* __restrict__ h, const float* __restrict__ chanS,
    const float* __restrict__ chanS2, const float* __restrict__ bn_g,
    const float* __restrict__ bn_b,
    const float* __restrict__ convo_w, const float* __restrict__ convo_b,
    const float* __restrict__ attno_w, const float* __restrict__ attno_b,
    const float* __restrict__ fc_w, const float* __restrict__ fc_b,
    float* __restrict__ out) {
  int b = blockIdx.x;
  int t = threadIdx.x;
  __shared__ float Sl[576];
  __shared__ float pooled[128];
  __shared__ float pa[40];
  if (t < 64) {
    int ci = t;
    float mu = chanS[ci] * (1.f / 16384.f);
    float var = chanS2[ci] * (1.f / 16384.f) - mu * mu;
    float sc = bn_g[ci] * rsqrtf(var + 1e-5f);
    float sh = bn_b[ci] - mu * sc;
    const float* hp = h + (size_t)(b * 64 + ci) * 1024;
    float h00 = fmaxf(0.f, hp[0] * sc + sh);
    float h0c = fmaxf(0.f, hp[31] * sc + sh);
    float hr0 = fmaxf(0.f, hp[992] * sc + sh);
    float hrc = fmaxf(0.f, hp[1023] * sc + sh);
    const float* sp = sstatP + (size_t)(b * 64 + ci) * 5;
    float T = sp[0], R0 = sp[1], R31 = sp[2], C0 = sp[3], C31 = sp[4];
    float xr[3] = {R31, 0.f, R0};
    float xc[3] = {C31, 0.f, C0};
    float corner[3][3] = {{hrc, 0.f, hr0}, {0.f, 0.f, 0.f}, {h0c, 0.f, h00}};
#pragma unroll
    for (int dy = 0; dy < 3; ++dy)
#pragma unroll
      for (int dx = 0; dx < 3; ++dx)
        Sl[ci * 9 + dy * 3 + dx] = T - xr[dy] - xc[dx] + corner[dy][dx];
  }
  if (t < 40) pa[t] = pooledA[b * 40 + t] * (1.f / 1024.f);
  __syncthreads();
  if (t < 88) {
    float acc = 0.f;
    for (int j = 0; j < 576; ++j) acc += convo_w[t * 576 + j] * Sl[j];
    pooled[t] = convo_b[t] + acc * (1.f / 1024.f);
  } else if (t < 128) {
    int co = t - 88;
    float acc = attno_b[co];
    for (int ci = 0; ci < 40; ++ci) acc += attno_w[co * 40 + ci] * pa[ci];
    pooled[88 + co] = acc;
  }
  __syncthreads();
  if (t < 100) {
    float acc = fc_b[t];
    for (int c = 0; c < 128; ++c) acc += fc_w[t * 128 + c] * pooled[c];
    out[b * 100 + t] = acc;
  }
}

extern "C" void kernel_launch(void* const* d_in, const int* in_sizes, int n_in,
                              void* d_out, int out_size, void* d_ws, size_t ws_size,
                              hipStream_t stream) {
  const float* x         = (const float*)d_in[0];
  const float* conv1_w   = (const float*)d_in[1];
  const float* conv1_b   = (const float*)d_in[2];
  const float* bn1_g     = (const float*)d_in[3];
  const float* bn1_b     = (const float*)d_in[4];
  const float* convo_w   = (const float*)d_in[5];
  const float* convo_b   = (const float*)d_in[6];
  const float* qkv_w     = (const float*)d_in[7];
  const float* qkv_b     = (const float*)d_in[8];
  const float* attno_w   = (const float*)d_in[9];
  const float* attno_b   = (const float*)d_in[10];
  const float* key_rel_h = (const float*)d_in[11];
  const float* key_rel_w = (const float*)d_in[12];
  const float* fc_w      = (const float*)d_in[13];
  const float* fc_b      = (const float*)d_in[14];

  float* ws      = (float*)d_ws;
  float* h       = ws + WS_H;
  float* qkvb    = ws + WS_QKV;
  float* chanS   = ws + WS_ACC;
  float* chanS2  = chanS + 64;
  float* sstatP  = chanS2 + 64;
  float* pooledA = sstatP + 5120;

  hipMemsetAsync(chanS, 0, ACC_BYTES, stream);
  conv1_kernel<<<1024, 256, 0, stream>>>(x, conv1_w, conv1_b, h, chanS, chanS2);
  qkv_kernel2<<<256, 256, 0, stream>>>(h, chanS, chanS2, bn1_g, bn1_b,
                                       qkv_w, qkv_b, qkvb, sstatP);
  attn_mfma_kernel<<<512, 256, 0, stream>>>(qkvb, key_rel_w, key_rel_h, pooledA);
  final_kernel<<<16, 128, 0, stream>>>(sstatP, pooledA, h, chanS, chanS2,
                                       bn1_g, bn1_b, convo_w, convo_b,
                                       attno_w, attno_b, fc_w, fc_b, (float*)d_out);
}

// Round 7
// 206.612 us; speedup vs baseline: 2.2091x; 1.0087x over previous
//
#include <hip/hip_runtime.h>
#include <hip/hip_bf16.h>

// SimpleAugmentedCNN forward, B=16, H=W=32, NH=4, DKH=DVH=10.
// memset -> conv1(LDS-staged, +BN-stat atomics) -> qkv3(BN+relu+sstat+1x1) ->
// attn_mfma (32x32x16 bf16; S^T=K.Q^T; rw via C-init, rh via spare dim10 from
//   packed regs; P->B-frag via __shfl_xor(32) register exchange (NO LDS
//   round-trip, no waitcnt); denom via ones-row in V; key-split 2) ->
// attn_combine (merge splits + faithful-reshape pool) -> final.
// conv_out / attention map / attn_pre never materialized.

#define WS_H     0                      // 16*64*1024   = 1048576 floats
#define WS_QKV   1048576                // 16*120*1024  = 1966080
#define WS_PART  3014656                // 65536*24     = 1572864
#define WS_ACC   4587520                // chanS 64 | chanS2 64 | sstatP 5120 | pooledA 640
#define ACC_BYTES ((64 + 64 + 5120 + 640) * 4)

typedef __attribute__((ext_vector_type(8))) short short8;
typedef __attribute__((ext_vector_type(16))) float float16;

__device__ __forceinline__ float fast_exp2(float x) {
#if __has_builtin(__builtin_amdgcn_exp2f)
  return __builtin_amdgcn_exp2f(x);
#else
  return exp2f(x);
#endif
}
__device__ __forceinline__ short f2bf(float x) {
  __hip_bfloat16 h(x);                 // RNE
  return *reinterpret_cast<short*>(&h);
}
__device__ __forceinline__ float bf2f(short s) {
  return __uint_as_float(((unsigned)(unsigned short)s) << 16);
}
__device__ __forceinline__ unsigned pack_bf16(float a, float b) {
  return (__float_as_uint(a) >> 16) | (__float_as_uint(b) & 0xFFFF0000u);
}

// ---------------- conv1: 3->64 3x3 SAME, LDS-staged x, 2 co/block -----------
// grid 512 = b*32 + cg (co pair). Thread = 4-px horizontal strip.
__global__ __launch_bounds__(256) void conv1_kernel(
    const float* __restrict__ x, const float* __restrict__ w,
    const float* __restrict__ bias, float* __restrict__ h,
    float* __restrict__ chanS, float* __restrict__ chanS2) {
  int b = blockIdx.x >> 5, cg = blockIdx.x & 31;
  int co0 = cg * 2;
  int t = threadIdx.x;
  __shared__ float xs[3072];
  const float4* xg = reinterpret_cast<const float4*>(x + b * 3072);
  float4* xsv = reinterpret_cast<float4*>(xs);
  for (int i = t; i < 768; i += 256) xsv[i] = xg[i];

  typedef const __attribute__((address_space(4))) float* cfp;
  cfp wc = (cfp)(size_t)w;
  float wr0[27], wr1[27];
#pragma unroll
  for (int i = 0; i < 27; ++i) { wr0[i] = wc[co0 * 27 + i]; wr1[i] = wc[(co0 + 1) * 27 + i]; }
  float bv0 = wc == nullptr ? 0.f : bias[co0];   // uniform loads
  float bv1 = bias[co0 + 1];
  __syncthreads();

  int row = t >> 3, col0 = (t & 7) * 4;
  float acc0[4] = {bv0, bv0, bv0, bv0};
  float acc1[4] = {bv1, bv1, bv1, bv1};
#pragma unroll
  for (int ci = 0; ci < 3; ++ci) {
#pragma unroll
    for (int dy = 0; dy < 3; ++dy) {
      int sr = row + dy - 1;
      if (sr < 0 || sr > 31) continue;
      const float* xr = &xs[ci * 1024 + sr * 32];
      float xv[6];
#pragma unroll
      for (int j = 0; j < 6; ++j) {
        int c = col0 - 1 + j;
        xv[j] = (c >= 0 && c < 32) ? xr[c] : 0.f;
      }
#pragma unroll
      for (int dx = 0; dx < 3; ++dx) {
        float w0 = wr0[ci * 9 + dy * 3 + dx], w1 = wr1[ci * 9 + dy * 3 + dx];
#pragma unroll
        for (int k = 0; k < 4; ++k) {
          acc0[k] += w0 * xv[k + dx];
          acc1[k] += w1 * xv[k + dx];
        }
      }
    }
  }
  float4 st0 = make_float4(acc0[0], acc0[1], acc0[2], acc0[3]);
  float4 st1 = make_float4(acc1[0], acc1[1], acc1[2], acc1[3]);
  *reinterpret_cast<float4*>(&h[(size_t)(b * 64 + co0) * 1024 + t * 4]) = st0;
  *reinterpret_cast<float4*>(&h[(size_t)(b * 64 + co0 + 1) * 1024 + t * 4]) = st1;

  float s10 = acc0[0] + acc0[1] + acc0[2] + acc0[3];
  float s20 = acc0[0]*acc0[0] + acc0[1]*acc0[1] + acc0[2]*acc0[2] + acc0[3]*acc0[3];
  float s11 = acc1[0] + acc1[1] + acc1[2] + acc1[3];
  float s21 = acc1[0]*acc1[0] + acc1[1]*acc1[1] + acc1[2]*acc1[2] + acc1[3]*acc1[3];
#pragma unroll
  for (int off = 32; off > 0; off >>= 1) {
    s10 += __shfl_down(s10, off);
    s20 += __shfl_down(s20, off);
    s11 += __shfl_down(s11, off);
    s21 += __shfl_down(s21, off);
  }
  if ((t & 63) == 0) {
    atomicAdd(&chanS[co0], s10);
    atomicAdd(&chanS2[co0], s20);
    atomicAdd(&chanS[co0 + 1], s11);
    atomicAdd(&chanS2[co0 + 1], s21);
  }
}

// ---------------- qkv3: BN-apply + relu + sstat partials + qkv 1x1 ----------
// grid 512 = b*32 + ck*2 + half (half = 60-co half). Wave handles 15 co.
__global__ __launch_bounds__(256) void qkv_kernel3(
    const float* __restrict__ h, const float* __restrict__ chanS,
    const float* __restrict__ chanS2, const float* __restrict__ bn_g,
    const float* __restrict__ bn_b, const float* __restrict__ qw,
    const float* __restrict__ qb, float* __restrict__ qkv,
    float* __restrict__ sstatP) {
  int bid = blockIdx.x;
  int half = bid & 1, ck = (bid >> 1) & 15, b = bid >> 5;
  int t = threadIdx.x;
  __shared__ float ssc[64], ssh[64];
  __shared__ float hs[64][65];
  if (t < 64) {
    float mu = chanS[t] * (1.f / 16384.f);
    float var = chanS2[t] * (1.f / 16384.f) - mu * mu;
    float sc = bn_g[t] * rsqrtf(var + 1e-5f);
    ssc[t] = sc;
    ssh[t] = bn_b[t] - mu * sc;
  }
  __syncthreads();
  int pos = t & 63, grp = t >> 6;
#pragma unroll
  for (int r = 0; r < 16; ++r) {
    int ci = r * 4 + grp;
    float v = h[(size_t)(b * 64 + ci) * 1024 + ck * 64 + pos];
    hs[ci][pos] = fmaxf(0.f, v * ssc[ci] + ssh[ci]);
  }
  __syncthreads();
  if (half == 0 && t < 128) {
    int ci = t >> 1, rl = t & 1;
    int row = ck * 2 + rl;
    const float* hp = &hs[ci][rl * 32];
    float T = 0.f;
#pragma unroll
    for (int k = 0; k < 32; ++k) T += hp[k];
    float* sp = sstatP + (size_t)(b * 64 + ci) * 5;
    atomicAdd(sp + 0, T);
    if (row == 0) atomicAdd(sp + 1, T);
    if (row == 31) atomicAdd(sp + 2, T);
    atomicAdd(sp + 3, hp[0]);
    atomicAdd(sp + 4, hp[31]);
  }
  int co0 = half * 60 + grp * 15;
  float acc[15];
#pragma unroll
  for (int j = 0; j < 15; ++j) acc[j] = 0.f;
  typedef const __attribute__((address_space(4))) float* cfp;
  cfp qwc = (cfp)(size_t)qw;
  for (int ci = 0; ci < 64; ++ci) {
    float hv = hs[ci][pos];
#pragma unroll
    for (int j = 0; j < 15; ++j) acc[j] += qwc[(co0 + j) * 64 + ci] * hv;
  }
#pragma unroll
  for (int j = 0; j < 15; ++j)
    qkv[(size_t)(b * 120 + co0 + j) * 1024 + ck * 64 + pos] = acc[j] + qb[co0 + j];
}

// ---------------- MFMA attention, key-split 2, register P-exchange ----------
// grid 1024 = ((b*4+hd)*8+qt)*2+ks. 4 waves; wave = 32 queries, 512 keys.
__global__ __launch_bounds__(256) void attn_mfma_kernel(
    const float* __restrict__ qkv, const float* __restrict__ relw,
    const float* __restrict__ relh, float* __restrict__ part) {
  int bid = blockIdx.x;
  int ks = bid & 1, qt = (bid >> 1) & 7, hd = (bid >> 4) & 3, b = bid >> 6;
  int t = threadIdx.x;
  int lane = t & 63, w = t >> 6, lid = lane & 31, hi = lane >> 5;

  __shared__ __align__(16) short Ks[256 * 24];   // [key][24] bf16 (d10=1, 11..15=0)
  __shared__ __align__(16) short Vs[16 * 264];   // [dim][264] bf16 (row10=1)

  short* Qs = Ks;                     // overlay [128][16] (setup only)
  float* RwL = (float*)Vs;            // [63][10] fp32 (setup only)
  float* RhL = RwL + 630;

  const float QS2 = 0.31622776601683794f * 1.4426950408889634f;  // dkh^-0.5 * log2e
  const float* qg = qkv + (size_t)(b * 120 + hd * 10) * 1024 + qt * 128;
  for (int i = t; i < 630; i += 256) {
    RwL[i] = relw[i];
    RhL[i] = relh[i];
  }
  for (int i = t; i < 1280; i += 256) {
    int q = i & 127, d = i >> 7;
    Qs[q * 16 + d] = f2bf(qg[d * 1024 + q] * QS2);
  }
  __syncthreads();

  int qrow = w * 32 + lid;            // block-local query
  float qfv[10];
#pragma unroll
  for (int d = 0; d < 10; ++d) qfv[d] = bf2f(Qs[qrow * 16 + d]);

  // rw C-init: rwC[r] = dot(q, Rw[31 + y'(r) - y(q)]), y(q)=lid
  float16 rwC;
#pragma unroll
  for (int r = 0; r < 16; ++r) {
    int yp = (r & 3) + 8 * (r >> 2) + 4 * hi;
    const float* rp = &RwL[(31 + yp - lid) * 10];
    float s = 0.f;
#pragma unroll
    for (int d = 0; d < 10; ++d) s += qfv[d] * rp[d];
    rwC[r] = s;
  }
  // rh for this query's 16 tiles (x' = ks*16 + 0..15), packed bf16 pairs
  int xn = qt * 4 + (qrow >> 5);
  unsigned rhp[8];
#pragma unroll
  for (int j = 0; j < 8; ++j) {
    const float* rpa = &RhL[(31 + ks * 16 + 2 * j - xn) * 10];
    const float* rpb = &RhL[(31 + ks * 16 + 2 * j + 1 - xn) * 10];
    float sa = 0.f, sb = 0.f;
#pragma unroll
    for (int d = 0; d < 10; ++d) { sa += qfv[d] * rpa[d]; sb += qfv[d] * rpb[d]; }
    rhp[j] = pack_bf16(sa, sb);
  }
  // Q B-frag (col=q, k=dims)
  short8 qf = *reinterpret_cast<const short8*>(&Qs[qrow * 16 + hi * 8]);
  short qf2 = qf[2];
  if (hi) { qf[3] = 0; qf[4] = 0; qf[5] = 0; qf[6] = 0; qf[7] = 0; }

  float16 O;
#pragma unroll
  for (int i = 0; i < 16; ++i) O[i] = 0.f;

  const float* kg = qkv + (size_t)(b * 120 + 40 + hd * 10) * 1024 + ks * 512;
  const float* vg = kg + 40 * 1024;

  for (int p = 0; p < 2; ++p) {
    __syncthreads();   // overlays consumed (p=0) / prev pass reads done
    for (int i = t; i < 2560; i += 256) {
      int d = i >> 8, key = i & 255;
      Ks[key * 24 + d] = f2bf(kg[d * 1024 + p * 256 + key]);
      Vs[d * 264 + key] = f2bf(vg[d * 1024 + p * 256 + key]);
    }
    Ks[t * 24 + 10] = (short)0x3F80;   // K dim10 = 1.0 (rh carrier)
#pragma unroll
    for (int d2 = 11; d2 < 16; ++d2) Ks[t * 24 + d2] = 0;  // NaN guard
    Vs[10 * 264 + t] = (short)0x3F80;  // ones-row (denominator)
    __syncthreads();

#pragma unroll
    for (int tt = 0; tt < 8; ++tt) {
      int Tl = p * 8 + tt;
      unsigned rhw = rhp[Tl >> 1];
      short rhu = (short)((Tl & 1) ? (rhw >> 16) : (rhw & 0xFFFFu));
      short8 bq = qf;
      bq[2] = hi ? rhu : qf2;
      short8 ak = *reinterpret_cast<const short8*>(&Ks[(tt * 32 + lid) * 24 + hi * 8]);
      float16 S = __builtin_amdgcn_mfma_f32_32x32x16_bf16(ak, bq, rwC, 0, 0, 0);
      // P = exp2(S); C reg r -> key row (r&3)+8*(r>>2)+4*hi
      float e[16];
#pragma unroll
      for (int i = 0; i < 16; ++i) e[i] = fast_exp2(S[i]);
      unsigned pe0 = pack_bf16(e[0], e[1]),  pe1 = pack_bf16(e[2], e[3]);
      unsigned pe2 = pack_bf16(e[4], e[5]),  pe3 = pack_bf16(e[6], e[7]);
      unsigned pe4 = pack_bf16(e[8], e[9]),  pe5 = pack_bf16(e[10], e[11]);
      unsigned pe6 = pack_bf16(e[12], e[13]), pe7 = pack_bf16(e[14], e[15]);
      // half-wave exchange: partner (lane^32) values
      unsigned px0 = (unsigned)__shfl_xor((int)pe0, 32);
      unsigned px1 = (unsigned)__shfl_xor((int)pe1, 32);
      unsigned px2 = (unsigned)__shfl_xor((int)pe2, 32);
      unsigned px3 = (unsigned)__shfl_xor((int)pe3, 32);
      unsigned px4 = (unsigned)__shfl_xor((int)pe4, 32);
      unsigned px5 = (unsigned)__shfl_xor((int)pe5, 32);
      unsigned px6 = (unsigned)__shfl_xor((int)pe6, 32);
      unsigned px7 = (unsigned)__shfl_xor((int)pe7, 32);
      // B-frags: lane j-element = key row hi*8+j
      uint4 b1u = hi ? make_uint4(px2, px3, pe2, pe3) : make_uint4(pe0, pe1, px0, px1);
      uint4 b2u = hi ? make_uint4(px6, px7, pe6, pe7) : make_uint4(pe4, pe5, px4, px5);
      short8 bp1 = *reinterpret_cast<short8*>(&b1u);
      short8 bp2 = *reinterpret_cast<short8*>(&b2u);
      short8 av1 = *reinterpret_cast<const short8*>(
          &Vs[(lid & 15) * 264 + tt * 32 + hi * 8]);
      short8 av2 = *reinterpret_cast<const short8*>(
          &Vs[(lid & 15) * 264 + tt * 32 + 16 + hi * 8]);
      O = __builtin_amdgcn_mfma_f32_32x32x16_bf16(av1, bp1, O, 0, 0, 0);
      O = __builtin_amdgcn_mfma_f32_32x32x16_bf16(av2, bp2, O, 0, 0, 0);
    }
  }

  // partials: [0..3]=d0..3, [4]=d8, [5]=d9, [6]=denom, [7]=pad, [8..11]=d4..7
  int qid = ((b * 4 + hd) * 8 + qt) * 128 + qrow;
  float* pb = part + (size_t)qid * 24 + ks * 12;
  if (!hi) {
    *reinterpret_cast<float4*>(pb) = make_float4(O[0], O[1], O[2], O[3]);
    *reinterpret_cast<float4*>(pb + 4) = make_float4(O[4], O[5], O[6], 0.f);
  } else {
    *reinterpret_cast<float4*>(pb + 8) = make_float4(O[0], O[1], O[2], O[3]);
  }
}

// ---------------- combine splits + faithful-reshape avg-pool ----------------
__global__ __launch_bounds__(256) void attn_combine_kernel(
    const float* __restrict__ part, float* __restrict__ pooledA) {
  __shared__ float pool[16];
  int t = threadIdx.x;
  if (t < 16) pool[t] = 0.f;
  __syncthreads();
  int qid = blockIdx.x * 256 + t;
  int bh = qid >> 10, n = qid & 1023;
  const float4* pp = reinterpret_cast<const float4*>(part + (size_t)qid * 24);
  float4 a0 = pp[0], a1 = pp[1], a2 = pp[2];
  float4 b0 = pp[3], b1 = pp[4], b2 = pp[5];
  float inv = 1.f / (a1.z + b1.z);
  float o[10];
  o[0] = (a0.x + b0.x) * inv; o[1] = (a0.y + b0.y) * inv;
  o[2] = (a0.z + b0.z) * inv; o[3] = (a0.w + b0.w) * inv;
  o[4] = (a2.x + b2.x) * inv; o[5] = (a2.y + b2.y) * inv;
  o[6] = (a2.z + b2.z) * inv; o[7] = (a2.w + b2.w) * inv;
  o[8] = (a1.x + b1.x) * inv; o[9] = (a1.y + b1.y) * inv;
  int f0 = n * 10;
  int c0 = f0 >> 10, c1 = (f0 + 9) >> 10;
  float s0 = 0.f, s1 = 0.f;
#pragma unroll
  for (int d = 0; d < 10; ++d) {
    if (((f0 + d) >> 10) == c0) s0 += o[d]; else s1 += o[d];
  }
  atomicAdd(&pool[c0], s0);
  if (c1 != c0) atomicAdd(&pool[c1], s1);
  __syncthreads();
  if (t < 10) atomicAdd(&pooledA[bh * 10 + t], pool[t]);
}

// ---------------- final: Sstat assembly + convo-pool matvec + attno + fc ----
__global__ __launch_bounds__(128) void final_kernel(
    const float* __restrict__ sstatP, const float* __restrict__ pooledA,
    const float* __restrict__ h, const float* __restrict__ chanS,
    const float* __restrict__ chanS2, const float* __restrict__ bn_g,
    const float* __restrict__ bn_b,
    const float* __restrict__ convo_w, const float* __restrict__ convo_b,
    const float* __restrict__ attno_w, const float* __restrict__ attno_b,
    const float* __restrict__ fc_w, const float* __restrict__ fc_b,
    float* __restrict__ out) {
  int b = blockIdx.x;
  int t = threadIdx.x;
  __shared__ float Sl[576];
  __shared__ float pooled[128];
  __shared__ float pa[40];
  if (t < 64) {
    int ci = t;
    float mu = chanS[ci] * (1.f / 16384.f);
    float var = chanS2[ci] * (1.f / 16384.f) - mu * mu;
    float sc = bn_g[ci] * rsqrtf(var + 1e-5f);
    float sh = bn_b[ci] - mu * sc;
    const float* hp = h + (size_t)(b * 64 + ci) * 1024;
    float h00 = fmaxf(0.f, hp[0] * sc + sh);
    float h0c = fmaxf(0.f, hp[31] * sc + sh);
    float hr0 = fmaxf(0.f, hp[992] * sc + sh);
    float hrc = fmaxf(0.f, hp[1023] * sc + sh);
    const float* sp = sstatP + (size_t)(b * 64 + ci) * 5;
    float T = sp[0], R0 = sp[1], R31 = sp[2], C0 = sp[3], C31 = sp[4];
    float xr[3] = {R31, 0.f, R0};
    float xc[3] = {C31, 0.f, C0};
    float corner[3][3] = {{hrc, 0.f, hr0}, {0.f, 0.f, 0.f}, {h0c, 0.f, h00}};
#pragma unroll
    for (int dy = 0; dy < 3; ++dy)
#pragma unroll
      for (int dx = 0; dx < 3; ++dx)
        Sl[ci * 9 + dy * 3 + dx] = T - xr[dy] - xc[dx] + corner[dy][dx];
  }
  if (t < 40) pa[t] = pooledA[b * 40 + t] * (1.f / 1024.f);
  __syncthreads();
  if (t < 88) {
    const float4* wr = reinterpret_cast<const float4*>(convo_w + t * 576);
    float acc = 0.f;
    for (int j = 0; j < 144; ++j) {
      float4 v = wr[j];
      acc += v.x * Sl[j * 4] + v.y * Sl[j * 4 + 1] + v.z * Sl[j * 4 + 2] + v.w * Sl[j * 4 + 3];
    }
    pooled[t] = convo_b[t] + acc * (1.f / 1024.f);
  } else if (t < 128) {
    int co = t - 88;
    const float4* wr = reinterpret_cast<const float4*>(attno_w + co * 40);
    float acc = attno_b[co];
    for (int j = 0; j < 10; ++j) {
      float4 v = wr[j];
      acc += v.x * pa[j * 4] + v.y * pa[j * 4 + 1] + v.z * pa[j * 4 + 2] + v.w * pa[j * 4 + 3];
    }
    pooled[88 + co] = acc;
  }
  __syncthreads();
  if (t < 100) {
    const float4* fr = reinterpret_cast<const float4*>(fc_w + t * 128);
    float acc = fc_b[t];
    for (int j = 0; j < 32; ++j) {
      float4 v = fr[j];
      acc += v.x * pooled[j * 4] + v.y * pooled[j * 4 + 1] + v.z * pooled[j * 4 + 2] + v.w * pooled[j * 4 + 3];
    }
    out[b * 100 + t] = acc;
  }
}

extern "C" void kernel_launch(void* const* d_in, const int* in_sizes, int n_in,
                              void* d_out, int out_size, void* d_ws, size_t ws_size,
                              hipStream_t stream) {
  const float* x         = (const float*)d_in[0];
  const float* conv1_w   = (const float*)d_in[1];
  const float* conv1_b   = (const float*)d_in[2];
  const float* bn1_g     = (const float*)d_in[3];
  const float* bn1_b     = (const float*)d_in[4];
  const float* convo_w   = (const float*)d_in[5];
  const float* convo_b   = (const float*)d_in[6];
  const float* qkv_w     = (const float*)d_in[7];
  const float* qkv_b     = (const float*)d_in[8];
  const float* attno_w   = (const float*)d_in[9];
  const float* attno_b   = (const float*)d_in[10];
  const float* key_rel_h = (const float*)d_in[11];
  const float* key_rel_w = (const float*)d_in[12];
  const float* fc_w      = (const float*)d_in[13];
  const float* fc_b      = (const float*)d_in[14];

  float* ws      = (float*)d_ws;
  float* h       = ws + WS_H;
  float* qkvb    = ws + WS_QKV;
  float* part    = ws + WS_PART;
  float* chanS   = ws + WS_ACC;
  float* chanS2  = chanS + 64;
  float* sstatP  = chanS2 + 64;
  float* pooledA = sstatP + 5120;

  hipMemsetAsync(chanS, 0, ACC_BYTES, stream);
  conv1_kernel<<<512, 256, 0, stream>>>(x, conv1_w, conv1_b, h, chanS, chanS2);
  qkv_kernel3<<<512, 256, 0, stream>>>(h, chanS, chanS2, bn1_g, bn1_b,
                                       qkv_w, qkv_b, qkvb, sstatP);
  attn_mfma_kernel<<<1024, 256, 0, stream>>>(qkvb, key_rel_w, key_rel_h, part);
  attn_combine_kernel<<<256, 256, 0, stream>>>(part, pooledA);
  final_kernel<<<16, 128, 0, stream>>>(sstatP, pooledA, h, chanS, chanS2,
                                       bn1_g, bn1_b, convo_w, convo_b,
                                       attno_w, attno_b, fc_w, fc_b, (float*)d_out);
}